// Round 1
// baseline (1130.407 us; speedup 1.0000x reference)
//
#include <hip/hip_runtime.h>

// Problem constants
#define NS   4
#define CIN  64
#define COUT 4
#define HH   96
#define WW   96
#define HWSZ 9216
#define DS   5
#define KD   1600      // CIN*DS*DS
#define ITER 20
#define SCS  16        // scalar slot padding (floats) to avoid atomic cacheline contention

static __device__ __forceinline__ float waveAllSum(float v) {
#pragma unroll
  for (int off = 32; off; off >>= 1) v += __shfl_xor(v, off);
  return v;
}

// corr[n,c1,c2,du,dv] = sum_{h,w} xs[n,c1,h,w] * xs[n,c2,h+du-4,w+dv-4]  (zero outside)
// Exploits corr[c1,c2,du,dv] = corr[c2,c1,8-du,8-dv]: only c1<=c2 blocks do work.
__global__ __launch_bounds__(256) void corr_kernel(const float* __restrict__ xs,
                                                   float* __restrict__ corr) {
  int bid = blockIdx.x;          // n*4096 + c1*64 + c2
  int n  = bid >> 12;
  int c1 = (bid >> 6) & 63;
  int c2 = bid & 63;
  if (c1 > c2) return;
  __shared__ float x2p[104 * 104];   // zero-padded shifted image (+4 halo)
  __shared__ float redbuf[4][81];
  const float* x1g = xs + (size_t)(n * CIN + c1) * HWSZ;
  const float* x2g = xs + (size_t)(n * CIN + c2) * HWSZ;
  int tid = threadIdx.x;
  for (int i = tid; i < 104 * 104; i += 256) x2p[i] = 0.f;
  __syncthreads();
  for (int i = tid; i < HWSZ; i += 256) {
    int h = i / 96, w = i - h * 96;
    x2p[(h + 4) * 104 + (w + 4)] = x2g[i];
  }
  __syncthreads();

  float acc[81];
#pragma unroll
  for (int k = 0; k < 81; ++k) acc[k] = 0.f;

  int tx = tid & 31, ty = tid >> 5;
  int w0 = tx * 3;                         // 32 threads * 3 cols = 96
  for (int h = ty; h < 96; h += 8) {       // 8 thread-rows * 12 iters = 96
    float a0 = x1g[h * 96 + w0];
    float a1 = x1g[h * 96 + w0 + 1];
    float a2 = x1g[h * 96 + w0 + 2];
#pragma unroll
    for (int du = 0; du < 9; ++du) {
      const float* rowp = &x2p[(h + du) * 104 + w0];
      float rbuf[11];
#pragma unroll
      for (int j = 0; j < 11; ++j) rbuf[j] = rowp[j];
#pragma unroll
      for (int dv = 0; dv < 9; ++dv) {
        acc[du * 9 + dv] += a0 * rbuf[dv] + a1 * rbuf[dv + 1] + a2 * rbuf[dv + 2];
      }
    }
  }

  int wave = tid >> 6, lane = tid & 63;
#pragma unroll
  for (int k = 0; k < 81; ++k) {           // static indexing (no scratch spill)
    float s = waveAllSum(acc[k]);
    if (lane == 0) redbuf[wave][k] = s;
  }
  __syncthreads();
  if (tid < 81) {
    float tot = redbuf[0][tid] + redbuf[1][tid] + redbuf[2][tid] + redbuf[3][tid];
    corr[((size_t)(n * CIN + c1) * CIN + c2) * 81 + tid] = tot;
    if (c1 != c2) {                        // mirror; skip when c1==c2 (avoid nondeterministic race)
      int du = tid / 9, dv = tid - du * 9;
      corr[((size_t)(n * CIN + c2) * CIN + c1) * 81 + (8 - du) * 9 + (8 - dv)] = tot;
    }
  }
}

// P[n, c*25+u*5+v, b] = sum_{h,w} xs[n,c,h+u-2,w+v-2]*ys[n,b,h,w] + a_n * d[n,b,c,u,v]
__global__ __launch_bounds__(256) void xty_kernel(const float* __restrict__ xs,
                                                  const float* __restrict__ ys,
                                                  const float* __restrict__ dd,
                                                  const float* __restrict__ alpha,
                                                  const float* __restrict__ reg,
                                                  float* __restrict__ P) {
  int bid = blockIdx.x;          // ((n*CIN)+c)*COUT + b
  int b = bid & 3;
  int c = (bid >> 2) & 63;
  int n = bid >> 8;
  __shared__ float xp[100 * 100];
  __shared__ float redbuf[4][25];
  const float* xg = xs + (size_t)(n * CIN + c) * HWSZ;
  const float* yg = ys + (size_t)(n * COUT + b) * HWSZ;
  int tid = threadIdx.x;
  for (int i = tid; i < 100 * 100; i += 256) xp[i] = 0.f;
  __syncthreads();
  for (int i = tid; i < HWSZ; i += 256) {
    int h = i / 96, w = i - h * 96;
    xp[(h + 2) * 100 + (w + 2)] = xg[i];
  }
  __syncthreads();

  float acc[25];
#pragma unroll
  for (int k = 0; k < 25; ++k) acc[k] = 0.f;
  int tx = tid & 31, ty = tid >> 5;
  int w0 = tx * 3;
  for (int h = ty; h < 96; h += 8) {
    float y0 = yg[h * 96 + w0];
    float y1 = yg[h * 96 + w0 + 1];
    float y2 = yg[h * 96 + w0 + 2];
#pragma unroll
    for (int u = 0; u < 5; ++u) {
      const float* rowp = &xp[(h + u) * 100 + w0];
      float rbuf[7];
#pragma unroll
      for (int j = 0; j < 7; ++j) rbuf[j] = rowp[j];
#pragma unroll
      for (int v = 0; v < 5; ++v) {
        acc[u * 5 + v] += y0 * rbuf[v] + y1 * rbuf[v + 1] + y2 * rbuf[v + 2];
      }
    }
  }
  int wave = tid >> 6, lane = tid & 63;
#pragma unroll
  for (int k = 0; k < 25; ++k) {
    float s = waveAllSum(acc[k]);
    if (lane == 0) redbuf[wave][k] = s;
  }
  __syncthreads();
  if (tid < 25) {
    float tot = redbuf[0][tid] + redbuf[1][tid] + redbuf[2][tid] + redbuf[3][tid];
    float a = alpha[n] * reg[0] * ((float)(HH * WW) / (float)(DS * DS * CIN));
    float dv = dd[((size_t)(n * COUT + b) * CIN + c) * 25 + tid];
    P[((size_t)(n * KD) + c * 25 + tid) * COUT + b] = tot + a * dv;
  }
}

// Q[n,p,q] = corr[n, c1,c2, j1-i1+4, j2-i2+4] (+ a_n on diagonal)
__global__ __launch_bounds__(256) void build_q_kernel(const float* __restrict__ corr,
                                                      const float* __restrict__ alpha,
                                                      const float* __restrict__ reg,
                                                      float* __restrict__ Q) {
  long long idx = (long long)blockIdx.x * 256 + threadIdx.x;
  const long long total = (long long)NS * KD * KD;
  if (idx >= total) return;
  int n   = (int)(idx / ((long long)KD * KD));
  int rem = (int)(idx % ((long long)KD * KD));
  int p = rem / KD, q = rem % KD;
  int c1 = p / 25, r1 = p % 25;
  int i1 = r1 / 5, i2 = r1 % 5;
  int c2 = q / 25, r2 = q % 25;
  int j1 = r2 / 5, j2 = r2 % 5;
  float v = corr[((size_t)(n * CIN + c1) * CIN + c2) * 81 + (j1 - i1 + 4) * 9 + (j2 - i2 + 4)];
  if (p == q) v += alpha[n] * reg[0] * ((float)(HH * WW) / (float)(DS * DS * CIN));
  Q[idx] = v;
}

// ---- CG (16 independent systems: 4 samples x 4 RHS columns; vectors laid out [n][row][col]) ----

__global__ __launch_bounds__(256) void cg_init_kernel(const float* __restrict__ P, float* __restrict__ x,
                                                      float* __restrict__ r, float* __restrict__ p,
                                                      float* __restrict__ rho0) {
  int idx = blockIdx.x * 256 + threadIdx.x;   // < 25600
  float pv = P[idx];
  x[idx] = 0.f; r[idx] = pv; p[idx] = pv;
  float part = pv * pv;
#pragma unroll
  for (int off = 4; off < 64; off <<= 1) part += __shfl_xor(part, off);
  __shared__ float lr[4][4];
  int wave = threadIdx.x >> 6, lane = threadIdx.x & 63;
  if (lane < 4) lr[wave][lane] = part;
  __syncthreads();
  if (threadIdx.x < 4) {
    int n = (blockIdx.x * 256) / 6400;
    float s = lr[0][threadIdx.x] + lr[1][threadIdx.x] + lr[2][threadIdx.x] + lr[3][threadIdx.x];
    atomicAdd(&rho0[(n * 4 + threadIdx.x) * SCS], s);
  }
}

// w = Q p ; pAp += p.w   (one wave per row, 4 RHS simultaneously)
__global__ __launch_bounds__(256) void cg_matvec_kernel(const float* __restrict__ Q, const float* __restrict__ p,
                                                        float* __restrict__ w, float* __restrict__ pAp) {
  int wave = threadIdx.x >> 6, lane = threadIdx.x & 63;
  int row = blockIdx.x * 4 + wave;            // 0..6399, all 4 rows in a block share n
  int n = row / KD;
  const float* qrow = Q + (size_t)row * KD;
  const float4* pv4 = (const float4*)(p + (size_t)n * KD * 4);
  float ax = 0.f, ay = 0.f, az = 0.f, aw = 0.f;
  for (int q = lane; q < KD; q += 64) {
    float qv = qrow[q];
    float4 pp = pv4[q];
    ax += qv * pp.x; ay += qv * pp.y; az += qv * pp.z; aw += qv * pp.w;
  }
  ax = waveAllSum(ax); ay = waveAllSum(ay); az = waveAllSum(az); aw = waveAllSum(aw);
  __shared__ float part[4][4];
  if (lane == 0) {
    float4 pr = ((const float4*)p)[row];
    ((float4*)w)[row] = make_float4(ax, ay, az, aw);
    part[wave][0] = ax * pr.x; part[wave][1] = ay * pr.y;
    part[wave][2] = az * pr.z; part[wave][3] = aw * pr.w;
  }
  __syncthreads();
  if (threadIdx.x < 4) {
    float s = part[0][threadIdx.x] + part[1][threadIdx.x] + part[2][threadIdx.x] + part[3][threadIdx.x];
    atomicAdd(&pAp[(n * 4 + threadIdx.x) * SCS], s);
  }
}

// alpha = rho/pAp ; x += alpha p ; r -= alpha w ; rho_new += r.r
__global__ __launch_bounds__(256) void cg_update_xr_kernel(float* __restrict__ x, float* __restrict__ r,
                                                           const float* __restrict__ p, const float* __restrict__ w,
                                                           const float* __restrict__ rho_k,
                                                           const float* __restrict__ pAp_k,
                                                           float* __restrict__ rho_k1) {
  int idx = blockIdx.x * 256 + threadIdx.x;   // < 25600
  int n = idx / 6400;
  int col = idx & 3;
  float alpha = rho_k[(n * 4 + col) * SCS] / pAp_k[(n * 4 + col) * SCS];
  x[idx] += alpha * p[idx];
  float rv = r[idx] - alpha * w[idx];
  r[idx] = rv;
  float part = rv * rv;
#pragma unroll
  for (int off = 4; off < 64; off <<= 1) part += __shfl_xor(part, off);
  __shared__ float lr[4][4];
  int wave = threadIdx.x >> 6, lane = threadIdx.x & 63;
  if (lane < 4) lr[wave][lane] = part;
  __syncthreads();
  if (threadIdx.x < 4) {
    float s = lr[0][threadIdx.x] + lr[1][threadIdx.x] + lr[2][threadIdx.x] + lr[3][threadIdx.x];
    atomicAdd(&rho_k1[(n * 4 + threadIdx.x) * SCS], s);
  }
}

// beta = rho_new/rho ; p = r + beta p
__global__ __launch_bounds__(256) void cg_update_p_kernel(float* __restrict__ p, const float* __restrict__ r,
                                                          const float* __restrict__ rho_k,
                                                          const float* __restrict__ rho_k1) {
  int idx = blockIdx.x * 256 + threadIdx.x;
  int n = idx / 6400;
  int col = idx & 3;
  float beta = rho_k1[(n * 4 + col) * SCS] / rho_k[(n * 4 + col) * SCS];
  p[idx] = r[idx] + beta * p[idx];
}

// out[n,b,c,i,j] = x[n, c*25+i*5+j, b]
__global__ __launch_bounds__(256) void write_out_kernel(const float* __restrict__ x, float* __restrict__ out) {
  int idx = blockIdx.x * 256 + threadIdx.x;   // 25600
  int n = idx / 6400;
  int rem = idx % 6400;
  int b = rem / 1600;
  int kk = rem % 1600;
  out[idx] = x[((size_t)n * KD + kk) * COUT + b];
}

extern "C" void kernel_launch(void* const* d_in, const int* in_sizes, int n_in,
                              void* d_out, int out_size, void* d_ws, size_t ws_size,
                              hipStream_t stream) {
  (void)in_sizes; (void)n_in; (void)out_size; (void)ws_size;
  const float* xs    = (const float*)d_in[0];   // [4,1,64,96,96]
  const float* dd    = (const float*)d_in[1];   // [4,4,64,5,5]
  const float* ys    = (const float*)d_in[2];   // [4,4,1,96,96]
  const float* alpha = (const float*)d_in[3];   // [4]
  const float* reg   = (const float*)d_in[4];   // [1]
  float* out = (float*)d_out;
  float* ws  = (float*)d_ws;

  const size_t SZ_Q    = (size_t)NS * KD * KD;          // 10,240,000 floats
  const size_t SZ_CORR = (size_t)NS * CIN * CIN * 81;   //  1,327,104
  const size_t SZ_V    = (size_t)NS * KD * COUT;        //     25,600
  float* Q    = ws;
  float* corr = Q + SZ_Q;
  float* P    = corr + SZ_CORR;
  float* X    = P + SZ_V;
  float* R    = X + SZ_V;
  float* PV   = R + SZ_V;
  float* WV   = PV + SZ_V;
  float* SC   = WV + SZ_V;                              // scalars (padded slots)
  float* rho  = SC;                                     // (ITER+1)*16 slots
  float* pAp  = SC + (size_t)(ITER + 1) * 16 * SCS;     // ITER*16 slots
  size_t sc_floats = (size_t)(2 * ITER + 1) * 16 * SCS; // total ws ~46.9 MB

  corr_kernel<<<NS * CIN * CIN, 256, 0, stream>>>(xs, corr);
  xty_kernel<<<NS * CIN * COUT, 256, 0, stream>>>(xs, ys, dd, alpha, reg, P);
  build_q_kernel<<<(int)((SZ_Q + 255) / 256), 256, 0, stream>>>(corr, alpha, reg, Q);
  hipMemsetAsync(SC, 0, sc_floats * sizeof(float), stream);
  cg_init_kernel<<<100, 256, 0, stream>>>(P, X, R, PV, rho);
  for (int k = 0; k < ITER; ++k) {
    cg_matvec_kernel<<<1600, 256, 0, stream>>>(Q, PV, WV, pAp + (size_t)k * 16 * SCS);
    cg_update_xr_kernel<<<100, 256, 0, stream>>>(X, R, PV, WV,
                                                 rho + (size_t)k * 16 * SCS,
                                                 pAp + (size_t)k * 16 * SCS,
                                                 rho + (size_t)(k + 1) * 16 * SCS);
    if (k + 1 < ITER)
      cg_update_p_kernel<<<100, 256, 0, stream>>>(PV, R,
                                                  rho + (size_t)k * 16 * SCS,
                                                  rho + (size_t)(k + 1) * 16 * SCS);
  }
  write_out_kernel<<<100, 256, 0, stream>>>(X, out);
}

// Round 2
// 464.438 us; speedup vs baseline: 2.4339x; 2.4339x over previous
//
#include <hip/hip_runtime.h>
#include <math.h>

// Problem constants
#define NS   4
#define CIN  64
#define COUT 4
#define HH   96
#define WW   96
#define HWSZ 9216
#define DS   5
#define KD   1600      // CIN*DS*DS
#define ITER 20

static __device__ __forceinline__ float waveAllSum(float v) {
#pragma unroll
  for (int off = 32; off; off >>= 1) v += __shfl_xor(v, off);
  return v;
}

static __device__ __forceinline__ float4 f4add(float4 a, float4 b) {
  return make_float4(a.x + b.x, a.y + b.y, a.z + b.z, a.w + b.w);
}
static __device__ __forceinline__ float4 f4sub(float4 a, float4 b) {
  return make_float4(a.x - b.x, a.y - b.y, a.z - b.z, a.w - b.w);
}
static __device__ __forceinline__ float4 f4mul(float4 a, float4 b) {
  return make_float4(a.x * b.x, a.y * b.y, a.z * b.z, a.w * b.w);
}
static __device__ __forceinline__ float4 f4div(float4 a, float4 b) {
  return make_float4(a.x / b.x, a.y / b.y, a.z / b.z, a.w / b.w);
}
static __device__ __forceinline__ float4 f4fma(float4 a, float4 b, float4 c) {
  return make_float4(fmaf(a.x, b.x, c.x), fmaf(a.y, b.y, c.y),
                     fmaf(a.z, b.z, c.z), fmaf(a.w, b.w, c.w));
}

// ---------------- corr kernel v2 ----------------
// corr[n,c1,c2,du,dv] = sum_{h,w} xs[n,c1,h,w] * x2pad[h+du, w+dv]
// (x2pad = x2 zero-padded by 4). Wave w owns du in {3w..3w+2}; lanes are
// 8 col-groups (12 cols) x 8 row-bands (12 rows). Sliding window over hp:
// each hp read once (5x ds_read_b128), x1 rows kept in a 3-slot register window.

template<int SMOD3, bool J0, bool J1, bool J2, bool LOADROW>
static __device__ __forceinline__ void corr_step(
    int s, int h0, int d0, int w0,
    const float* __restrict__ x1g, const float* __restrict__ x2p,
    float (&x1w)[3][12], float (&acc)[27]) {
  int hp = h0 + d0 + s;
  float xr[20];
  const float4* rp = (const float4*)(x2p + hp * 104 + w0);
  *(float4*)&xr[0]  = rp[0];
  *(float4*)&xr[4]  = rp[1];
  *(float4*)&xr[8]  = rp[2];
  *(float4*)&xr[12] = rp[3];
  *(float4*)&xr[16] = rp[4];
  if (LOADROW) {
    const float4* xrow = (const float4*)(x1g + (h0 + s) * 96 + w0);
    *(float4*)&x1w[SMOD3][0] = xrow[0];
    *(float4*)&x1w[SMOD3][4] = xrow[1];
    *(float4*)&x1w[SMOD3][8] = xrow[2];
  }
  if (J0) {   // j=0, row r=s, slot SMOD3
#pragma unroll
    for (int c = 0; c < 12; ++c)
#pragma unroll
      for (int dv = 0; dv < 9; ++dv)
        acc[0 * 9 + dv] += x1w[SMOD3][c] * xr[c + dv];
  }
  if (J1) {   // j=1, row r=s-1, slot (SMOD3+2)%3
#pragma unroll
    for (int c = 0; c < 12; ++c)
#pragma unroll
      for (int dv = 0; dv < 9; ++dv)
        acc[1 * 9 + dv] += x1w[(SMOD3 + 2) % 3][c] * xr[c + dv];
  }
  if (J2) {   // j=2, row r=s-2, slot (SMOD3+1)%3
#pragma unroll
    for (int c = 0; c < 12; ++c)
#pragma unroll
      for (int dv = 0; dv < 9; ++dv)
        acc[2 * 9 + dv] += x1w[(SMOD3 + 1) % 3][c] * xr[c + dv];
  }
}

__global__ __launch_bounds__(192) void corr_kernel(const float* __restrict__ xs,
                                                   float* __restrict__ corr) {
  // compact triangular grid: 4 * 2080 blocks, pair (c1<=c2)
  int pid = blockIdx.x;
  int n = pid / 2080;
  int t = pid - n * 2080;
  int c1 = (int)((129.0f - sqrtf((float)(16641 - 8 * t))) * 0.5f);
  while (c1 > 0 && (c1 * (129 - c1)) / 2 > t) --c1;
  while (((c1 + 1) * (128 - c1)) / 2 <= t) ++c1;
  int c2 = c1 + (t - (c1 * (129 - c1)) / 2);

  __shared__ float x2p[104 * 104];
  int tid = threadIdx.x;
  const float* x1g = xs + (size_t)(n * CIN + c1) * HWSZ;
  const float* x2g = xs + (size_t)(n * CIN + c2) * HWSZ;

  float4* x2p4 = (float4*)x2p;
  for (int i = tid; i < 2704; i += 192) x2p4[i] = make_float4(0.f, 0.f, 0.f, 0.f);
  __syncthreads();
  for (int i = tid; i < 2304; i += 192) {
    int h = i / 24, c4 = i - h * 24;
    x2p4[(h + 4) * 26 + 1 + c4] = ((const float4*)x2g)[h * 24 + c4];
  }
  __syncthreads();

  int wid = tid >> 6, lane = tid & 63;
  int g = lane & 7, band = lane >> 3;
  int w0 = 12 * g, h0 = 12 * band, d0 = 3 * wid;

  float acc[27];
#pragma unroll
  for (int k = 0; k < 27; ++k) acc[k] = 0.f;
  float x1w[3][12];

  corr_step<0, true, false, false, true>(0, h0, d0, w0, x1g, x2p, x1w, acc);
  corr_step<1, true, true,  false, true>(1, h0, d0, w0, x1g, x2p, x1w, acc);
  for (int sb = 2; sb <= 8; sb += 3) {   // s = 2..10, sb ≡ 2 (mod 3)
    corr_step<2, true, true, true, true>(sb,     h0, d0, w0, x1g, x2p, x1w, acc);
    corr_step<0, true, true, true, true>(sb + 1, h0, d0, w0, x1g, x2p, x1w, acc);
    corr_step<1, true, true, true, true>(sb + 2, h0, d0, w0, x1g, x2p, x1w, acc);
  }
  corr_step<2, true,  true, true, true >(11, h0, d0, w0, x1g, x2p, x1w, acc);
  corr_step<0, false, true, true, false>(12, h0, d0, w0, x1g, x2p, x1w, acc);
  corr_step<1, false, false, true, false>(13, h0, d0, w0, x1g, x2p, x1w, acc);

  // wave-internal full reduction (each wave fully owns its 3 du values)
#pragma unroll
  for (int k = 0; k < 27; ++k) {
    float v = acc[k];
#pragma unroll
    for (int off = 1; off < 64; off <<= 1) v += __shfl_xor(v, off);
    acc[k] = v;
  }
  if (lane == 0) {
    size_t pbase = ((size_t)((n * CIN + c1) * CIN + c2)) * 81;
#pragma unroll
    for (int k = 0; k < 27; ++k) {
      int du = d0 + k / 9, dvv = k % 9;
      corr[pbase + du * 9 + dvv] = acc[k];
    }
    if (c1 != c2) {
      size_t mbase = ((size_t)((n * CIN + c2) * CIN + c1)) * 81;
#pragma unroll
      for (int k = 0; k < 27; ++k) {
        int du = d0 + k / 9, dvv = k % 9;
        corr[mbase + (8 - du) * 9 + (8 - dvv)] = acc[k];
      }
    }
  }
}

// ---------------- xty kernel (unchanged from round 1) ----------------
__global__ __launch_bounds__(256) void xty_kernel(const float* __restrict__ xs,
                                                  const float* __restrict__ ys,
                                                  const float* __restrict__ dd,
                                                  const float* __restrict__ alpha,
                                                  const float* __restrict__ reg,
                                                  float* __restrict__ P) {
  int bid = blockIdx.x;          // ((n*CIN)+c)*COUT + b
  int b = bid & 3;
  int c = (bid >> 2) & 63;
  int n = bid >> 8;
  __shared__ float xp[100 * 100];
  __shared__ float redbuf[4][25];
  const float* xg = xs + (size_t)(n * CIN + c) * HWSZ;
  const float* yg = ys + (size_t)(n * COUT + b) * HWSZ;
  int tid = threadIdx.x;
  for (int i = tid; i < 100 * 100; i += 256) xp[i] = 0.f;
  __syncthreads();
  for (int i = tid; i < HWSZ; i += 256) {
    int h = i / 96, w = i - h * 96;
    xp[(h + 2) * 100 + (w + 2)] = xg[i];
  }
  __syncthreads();

  float acc[25];
#pragma unroll
  for (int k = 0; k < 25; ++k) acc[k] = 0.f;
  int tx = tid & 31, ty = tid >> 5;
  int w0 = tx * 3;
  for (int h = ty; h < 96; h += 8) {
    float y0 = yg[h * 96 + w0];
    float y1 = yg[h * 96 + w0 + 1];
    float y2 = yg[h * 96 + w0 + 2];
#pragma unroll
    for (int u = 0; u < 5; ++u) {
      const float* rowp = &xp[(h + u) * 100 + w0];
      float rbuf[7];
#pragma unroll
      for (int j = 0; j < 7; ++j) rbuf[j] = rowp[j];
#pragma unroll
      for (int v = 0; v < 5; ++v) {
        acc[u * 5 + v] += y0 * rbuf[v] + y1 * rbuf[v + 1] + y2 * rbuf[v + 2];
      }
    }
  }
  int wave = tid >> 6, lane = tid & 63;
#pragma unroll
  for (int k = 0; k < 25; ++k) {
    float s = waveAllSum(acc[k]);
    if (lane == 0) redbuf[wave][k] = s;
  }
  __syncthreads();
  if (tid < 25) {
    float tot = redbuf[0][tid] + redbuf[1][tid] + redbuf[2][tid] + redbuf[3][tid];
    float a = alpha[n] * reg[0] * ((float)(HH * WW) / (float)(DS * DS * CIN));
    float dv = dd[((size_t)(n * COUT + b) * CIN + c) * 25 + tid];
    P[((size_t)(n * KD) + c * 25 + tid) * COUT + b] = tot + a * dv;
  }
}

// ---------------- fused CG iteration ----------------
// One launch per iteration; block (n,c1) redundantly recomputes the full
// r/p vectors and the rho/pAp dot products (identical order in every block ->
// bitwise consistent, no atomics). Cross-block buffers (R, W, PEFF) are
// ping-ponged between launches so there are no intra-launch races.
// Matvec uses corr directly: w[(c1,i),col] = sum_{c2,j} corr[n,c1,c2,idx(i,j)] * p[(c2,j),col] + a*p[(c1,i),col]

static __device__ __forceinline__ void allreduce2_f4(float4& a, float4& b,
                                                     float4* redA, float4* redB, int tid) {
#pragma unroll
  for (int off = 1; off < 64; off <<= 1) {
    a.x += __shfl_xor(a.x, off); a.y += __shfl_xor(a.y, off);
    a.z += __shfl_xor(a.z, off); a.w += __shfl_xor(a.w, off);
    b.x += __shfl_xor(b.x, off); b.y += __shfl_xor(b.y, off);
    b.z += __shfl_xor(b.z, off); b.w += __shfl_xor(b.w, off);
  }
  int wid = tid >> 6;
  if ((tid & 63) == 0) { redA[wid] = a; redB[wid] = b; }
  __syncthreads();
  float4 sa = f4add(f4add(redA[0], redA[1]), f4add(redA[2], redA[3]));
  float4 sb = f4add(f4add(redB[0], redB[1]), f4add(redB[2], redB[3]));
  __syncthreads();
  a = sa; b = sb;
}

__global__ __launch_bounds__(256) void cg_iter_kernel(
    const float* __restrict__ corr, const float* __restrict__ P,
    const float* __restrict__ Rin, float* __restrict__ Rout,
    const float* __restrict__ Win, float* __restrict__ Wout,
    const float* __restrict__ PFin, float* __restrict__ PFout,
    float* __restrict__ X,
    const float* __restrict__ ralpha, const float* __restrict__ rreg,
    int first) {
  __shared__ float corrS[64 * 84];            // padded rows (84) for aligned b128
  __shared__ float4 pS[KD];                   // current p, all 4 cols
  __shared__ float4 redA[4], redB[4];
  __shared__ float redW[4][25][4];

  int b = blockIdx.x;
  int n = b >> 6, c1 = b & 63;
  int tid = threadIdx.x;

  // stage corr slab [c2=0..63][81]
  const float* cgp = corr + ((size_t)(n * CIN + c1)) * CIN * 81;
  for (int i = tid; i < 5184; i += 256) corrS[(i / 81) * 84 + (i % 81)] = cgp[i];

  const float4* Rin4 = (const float4*)Rin + (size_t)n * KD;
  const float4* Win4 = (const float4*)Win + (size_t)n * KD;
  const float4* PFin4 = (const float4*)PFin + (size_t)n * KD;
  const float4* P4 = (const float4*)P + (size_t)n * KD;
  float4* Rout4 = (float4*)Rout + (size_t)n * KD;
  float4* PFout4 = (float4*)PFout + (size_t)n * KD;
  float4* X4 = (float4*)X + (size_t)n * KD;

  const float4 zero4 = make_float4(0.f, 0.f, 0.f, 0.f);
  float4 rv[7], wv[7], pv[7];
#pragma unroll
  for (int t = 0; t < 7; ++t) {
    int idx = tid + 256 * t;
    bool ok = idx < KD;
    if (first) {
      rv[t] = ok ? P4[idx] : zero4;
      wv[t] = zero4; pv[t] = zero4;
    } else {
      rv[t] = ok ? Rin4[idx] : zero4;
      wv[t] = ok ? Win4[idx] : zero4;
      pv[t] = ok ? PFin4[idx] : zero4;
    }
  }
  float4 rho_prev = zero4, pAp = zero4;
#pragma unroll
  for (int t = 0; t < 7; ++t) {
    rho_prev = f4fma(rv[t], rv[t], rho_prev);
    pAp = f4fma(pv[t], wv[t], pAp);
  }
  allreduce2_f4(rho_prev, pAp, redA, redB, tid);

  float4 av = first ? zero4 : f4div(rho_prev, pAp);   // alpha_{k-1}

  // r_k = r_{k-1} - alpha*w ; rho_k
  float4 rho_k = zero4;
#pragma unroll
  for (int t = 0; t < 7; ++t) {
    rv[t] = f4sub(rv[t], f4mul(av, wv[t]));
    rho_k = f4fma(rv[t], rv[t], rho_k);
  }
  // x update (own rows only)
  int lo = c1 * 25;
#pragma unroll
  for (int t = 0; t < 7; ++t) {
    int idx = tid + 256 * t;
    if (idx >= lo && idx < lo + 25) {
      if (first) X4[idx] = zero4;
      else X4[idx] = f4fma(av, pv[t], X4[idx]);
    }
  }
  float4 dummy = zero4;
  allreduce2_f4(rho_k, dummy, redA, redB, tid);

  float4 bv = first ? zero4 : f4div(rho_k, rho_prev);

  // p_k = r_k + beta*p_{k-1}; stash in LDS, write own rows to global
#pragma unroll
  for (int t = 0; t < 7; ++t) {
    int idx = tid + 256 * t;
    if (idx < KD) {
      float4 pnew = f4fma(bv, pv[t], rv[t]);
      pS[idx] = pnew;
      if (idx >= lo && idx < lo + 25) {
        PFout4[idx] = pnew;
        Rout4[idx] = rv[t];
      }
    }
  }
  __syncthreads();

  // matvec: thread = (c2, col)
  int c2 = tid >> 2, col = tid & 3;
  float creg[81];
#pragma unroll
  for (int t4 = 0; t4 < 20; ++t4)
    *(float4*)&creg[4 * t4] = *(const float4*)&corrS[c2 * 84 + 4 * t4];
  creg[80] = corrS[c2 * 84 + 80];

  float a25[25];
#pragma unroll
  for (int i = 0; i < 25; ++i) a25[i] = 0.f;
  const float* pSf = (const float*)pS;
#pragma unroll
  for (int j = 0; j < 25; ++j) {
    float pvv = pSf[(c2 * 25 + j) * 4 + col];
#pragma unroll
    for (int i = 0; i < 25; ++i) {
      const int i1 = i / 5, i2 = i % 5, j1 = j / 5, j2 = j % 5;
      a25[i] += creg[(j1 - i1 + 4) * 9 + (j2 - i2 + 4)] * pvv;
    }
  }
  // reduce over the wave's 16 c2 values (lane bits 2..5)
#pragma unroll
  for (int i = 0; i < 25; ++i) {
    float v = a25[i];
    v += __shfl_xor(v, 4); v += __shfl_xor(v, 8);
    v += __shfl_xor(v, 16); v += __shfl_xor(v, 32);
    a25[i] = v;
  }
  int wid = tid >> 6;
  if ((tid & 63) < 4) {
#pragma unroll
    for (int i = 0; i < 25; ++i) redW[wid][i][col] = a25[i];
  }
  __syncthreads();
  if (tid < 100) {
    int i = tid >> 2, cc = tid & 3;
    float wval = redW[0][i][cc] + redW[1][i][cc] + redW[2][i][cc] + redW[3][i][cc];
    float aa = ralpha[n] * rreg[0] * ((float)(HH * WW) / (float)(DS * DS * CIN));
    int row = lo + i;
    wval = fmaf(aa, pSf[row * 4 + cc], wval);
    Wout[((size_t)n * KD + row) * 4 + cc] = wval;
  }
}

// ---------------- finalize: x += alpha_19 * p_19, write transposed output ----------------
__global__ __launch_bounds__(256) void cg_final_kernel(
    const float* __restrict__ Rin, const float* __restrict__ Win,
    const float* __restrict__ PFin, const float* __restrict__ X,
    float* __restrict__ out) {
  __shared__ float4 redA[4], redB[4];
  int b = blockIdx.x;
  int n = b >> 6, c1 = b & 63;
  int tid = threadIdx.x;

  const float4* Rin4 = (const float4*)Rin + (size_t)n * KD;
  const float4* Win4 = (const float4*)Win + (size_t)n * KD;
  const float4* PFin4 = (const float4*)PFin + (size_t)n * KD;
  const float4 zero4 = make_float4(0.f, 0.f, 0.f, 0.f);

  float4 rho = zero4, pAp = zero4;
#pragma unroll
  for (int t = 0; t < 7; ++t) {
    int idx = tid + 256 * t;
    if (idx < KD) {
      float4 r = Rin4[idx], w = Win4[idx], p = PFin4[idx];
      rho = f4fma(r, r, rho);
      pAp = f4fma(p, w, pAp);
    }
  }
  allreduce2_f4(rho, pAp, redA, redB, tid);
  float4 av = f4div(rho, pAp);

  if (tid < 100) {
    int i = tid >> 2, cc = tid & 3;
    int row = c1 * 25 + i;
    float a_cc = (cc == 0) ? av.x : (cc == 1) ? av.y : (cc == 2) ? av.z : av.w;
    float xv = X[((size_t)n * KD + row) * 4 + cc] + a_cc * PFin[((size_t)n * KD + row) * 4 + cc];
    out[((size_t)(n * 4 + cc) * 64 + c1) * 25 + i] = xv;
  }
}

extern "C" void kernel_launch(void* const* d_in, const int* in_sizes, int n_in,
                              void* d_out, int out_size, void* d_ws, size_t ws_size,
                              hipStream_t stream) {
  (void)in_sizes; (void)n_in; (void)out_size; (void)ws_size;
  const float* xs    = (const float*)d_in[0];   // [4,1,64,96,96]
  const float* dd    = (const float*)d_in[1];   // [4,4,64,5,5]
  const float* ys    = (const float*)d_in[2];   // [4,4,1,96,96]
  const float* alpha = (const float*)d_in[3];   // [4]
  const float* reg   = (const float*)d_in[4];   // [1]
  float* out = (float*)d_out;
  float* ws  = (float*)d_ws;

  const size_t SZ_CORR = (size_t)NS * CIN * CIN * 81;   // 1,327,104
  const size_t SZ_V    = (size_t)NS * KD * COUT;        // 25,600
  float* corr = ws;
  float* P    = corr + SZ_CORR;
  float* X    = P + SZ_V;
  float* R0   = X + SZ_V;
  float* R1   = R0 + SZ_V;
  float* W0   = R1 + SZ_V;
  float* W1   = W0 + SZ_V;
  float* PF0  = W1 + SZ_V;
  float* PF1  = PF0 + SZ_V;
  float* Rb[2] = {R0, R1};
  float* Wb[2] = {W0, W1};
  float* Pb[2] = {PF0, PF1};

  corr_kernel<<<NS * 2080, 192, 0, stream>>>(xs, corr);
  xty_kernel<<<NS * CIN * COUT, 256, 0, stream>>>(xs, ys, dd, alpha, reg, P);
  for (int k = 0; k < ITER; ++k) {
    cg_iter_kernel<<<NS * CIN, 256, 0, stream>>>(
        corr, P,
        Rb[k & 1], Rb[(k + 1) & 1],
        Wb[k & 1], Wb[(k + 1) & 1],
        Pb[k & 1], Pb[(k + 1) & 1],
        X, alpha, reg, k == 0 ? 1 : 0);
  }
  cg_final_kernel<<<NS * CIN, 256, 0, stream>>>(Rb[0], Wb[0], Pb[0], X, out);
}